// Round 2
// baseline (420.369 us; speedup 1.0000x reference)
//
#include <hip/hip_runtime.h>
#include <math.h>

// ---------------------------------------------------------------------------
// EigenLoss: faithful re-implementation of the JAX reference, including a
// LAPACK-sgeev-equivalent (sgebal 'B' -> sgehd2 -> slahqr/slanv2) eigenvalue
// solver for 5x5 real matrices, because the reference output depends on the
// LAPACK eigenvalue ORDER (cumsum in select_best_k, elementwise ev diff).
// jax CPU lowering passes matrices COLUMN-MAJOR to sgeev -> we solve lap
// itself (not lap^T); h[] is column-major below.
//
// Pipeline:
//   eig_init  (1 block): deg vectors (batches 0..4), 32-pattern true-eig table
//   eig_main  (B threads): per-batch pred 5x5 eigensolve + accumulation
//   eig_final (1 block): energies -> min_k -> distance
// ---------------------------------------------------------------------------

#define DEV __device__ __forceinline__
#define STRIDE 35   // per-thread LDS floats: 25 (H) + 5 (WR) + 5 (WI)

static DEV float slapy2f(float x, float y){
#pragma clang fp contract(off)
  float xa = fabsf(x), ya = fabsf(y);
  float w = fmaxf(xa, ya), z = fminf(xa, ya);
  if (z == 0.f) return w;
  float r = z / w;
  return w * sqrtf(1.f + r*r);
}

// LAPACK slarfg on a contiguous vector (alpha, x[0..n-2]); returns tau.
static DEV float slarfg_col(int n, float* alpha, float* x){
#pragma clang fp contract(off)
  if (n <= 1) return 0.f;
  int m = n - 1;
  float xnorm;
  if (m == 1) xnorm = fabsf(x[0]);
  else {
    float scl = 0.f, ssq = 1.f;       // reference-BLAS snrm2 (ssq form)
    for (int i = 0; i < m; ++i){
      float xi = x[i];
      if (xi != 0.f){
        float ax = fabsf(xi);
        if (scl < ax){ float r = scl/ax; ssq = 1.f + ssq*(r*r); scl = ax; }
        else         { float r = ax/scl; ssq = ssq + r*r; }
      }
    }
    xnorm = scl * sqrtf(ssq);
  }
  if (xnorm == 0.f) return 0.f;
  float a = *alpha;
  float beta = -copysignf(slapy2f(a, xnorm), a);
  float tau = (beta - a) / beta;
  float sc = 1.f / (a - beta);
  for (int i = 0; i < m; ++i) x[i] *= sc;
  *alpha = beta;
  return tau;
}

// slarfg specialized for the slahqr sweep vectors (nr in {2,3}, registers).
static DEV float slarfg23(int nr, float* alpha, float* x1, float* x2){
#pragma clang fp contract(off)
  float xnorm;
  if (nr == 2) xnorm = fabsf(*x1);
  else {
    float scl = 0.f, ssq = 1.f;
    float v = *x1;
    if (v != 0.f){ float ax = fabsf(v); if (scl < ax){ float r=scl/ax; ssq=1.f+ssq*(r*r); scl=ax; } else { float r=ax/scl; ssq+=r*r; } }
    v = *x2;
    if (v != 0.f){ float ax = fabsf(v); if (scl < ax){ float r=scl/ax; ssq=1.f+ssq*(r*r); scl=ax; } else { float r=ax/scl; ssq+=r*r; } }
    xnorm = scl*sqrtf(ssq);
  }
  if (xnorm == 0.f) return 0.f;
  float a = *alpha;
  float beta = -copysignf(slapy2f(a, xnorm), a);
  float tau = (beta - a)/beta;
  float sc = 1.f/(a - beta);
  *x1 *= sc;
  if (nr == 3) *x2 *= sc;
  *alpha = beta;
  return tau;
}

// LAPACK slanv2 (eigenvalues-only use; rotation outputs dropped).
static DEV void slanv2f(float a, float b, float c, float d,
                        float* rt1r, float* rt1i, float* rt2r, float* rt2i){
#pragma clang fp contract(off)
  const float eps = 1.1920929e-7f;    // slamch('P')
  if (c == 0.f){
    // nothing
  } else if (b == 0.f){
    float t = d; d = a; a = t; b = -c; c = 0.f;
  } else if ((a - d) == 0.f && copysignf(1.f,b) != copysignf(1.f,c)){
    // standardized already
  } else {
    float temp = a - d;
    float p = 0.5f*temp;
    float bcmax = fmaxf(fabsf(b), fabsf(c));
    float bcmis = fminf(fabsf(b), fabsf(c)) * copysignf(1.f,b) * copysignf(1.f,c);
    float scale = fmaxf(fabsf(p), bcmax);
    float z = (p/scale)*p + (bcmax/scale)*bcmis;
    if (z >= 4.f*eps){
      z = p + copysignf(sqrtf(scale)*sqrtf(z), p);
      a = d + z;
      d = d - (bcmax/z)*bcmis;
      b = b - c;
      c = 0.f;
    } else {
      float sigma = b + c;
      float tau = slapy2f(sigma, temp);
      float cs = sqrtf(0.5f*(1.f + fabsf(sigma)/tau));
      float sn = -(p/(tau*cs))*copysignf(1.f, sigma);
      float aa = a*cs + b*sn,  bb = -a*sn + b*cs;
      float cc = c*cs + d*sn,  dd = -c*sn + d*cs;
      a = aa*cs + cc*sn;  b = bb*cs + dd*sn;
      c = -aa*sn + cc*cs; d = -bb*sn + dd*cs;
      temp = 0.5f*(a+d);
      a = temp; d = temp;
      if (c != 0.f){
        if (b != 0.f){
          if (copysignf(1.f,b) == copysignf(1.f,c)){
            float sab = sqrtf(fabsf(b)), sac = sqrtf(fabsf(c));
            p = copysignf(sab*sac, c);
            a = temp + p; d = temp - p;
            b = b - c; c = 0.f;
          }
        } else {
          b = -c; c = 0.f;
        }
      }
    }
  }
  *rt1r = a; *rt2r = d;
  if (c == 0.f){ *rt1i = 0.f; *rt2i = 0.f; }
  else { *rt1i = sqrtf(fabsf(b))*sqrtf(fabsf(c)); *rt2i = -(*rt1i); }
}

// sgeev ('N','N') pipeline for a 5x5 real matrix stored column-major in LDS.
static __device__ void sgeev5(float* __restrict__ h,
                              float* __restrict__ wr, float* __restrict__ wi){
#pragma clang fp contract(off)
#define A_(i,j) h[((j)-1)*5 + ((i)-1)]
#define WR_(i) wr[(i)-1]
#define WI_(i) wi[(i)-1]
  const int n = 5;
  int k = 1, l = 5;
  float scl[5] = {1.f,1.f,1.f,1.f,1.f};
  bool balDone = false;

  // ---- sgebal 'B': permutation, row phase (push isolated rows to bottom) ----
  {
    bool again = true;
    while (again){
      again = false;
      for (int j = l; j >= 1; --j){
        bool iso = true;
        for (int i2 = 1; i2 <= l; ++i2){
          if (i2 == j) continue;
          if (A_(j,i2) != 0.f){ iso = false; break; }
        }
        if (iso){
          if (j != l){
            for (int r = 1; r <= l; ++r){ float t = A_(r,j); A_(r,j) = A_(r,l); A_(r,l) = t; }
            for (int c = k; c <= n; ++c){ float t = A_(j,c); A_(j,c) = A_(l,c); A_(l,c) = t; }
          }
          l -= 1;
          if (l == 1) balDone = true;   // netlib: GOTO 210 (skip rest of gebal)
          else again = true;
          break;
        }
      }
      if (balDone) break;
    }
  }
  if (!balDone){
    // ---- permutation, column phase (push isolated columns to top) ----
    bool again = true;
    while (again){
      again = false;
      for (int j = k; j <= l; ++j){
        bool iso = true;
        for (int i2 = k; i2 <= l; ++i2){
          if (i2 == j) continue;
          if (A_(i2,j) != 0.f){ iso = false; break; }
        }
        if (iso){
          if (j != k){
            for (int r = 1; r <= l; ++r){ float t = A_(r,j); A_(r,j) = A_(r,k); A_(r,k) = t; }
            for (int c = k; c <= n; ++c){ float t = A_(j,c); A_(j,c) = A_(k,c); A_(k,c) = t; }
          }
          k += 1;
          again = true;
          break;
        }
      }
    }
    // ---- iterative power-of-2 scaling ----
    const float sclfac = 2.f, factor = 0.95f;
    const float sfmin1 = 1.17549435e-38f / 1.1920929e-7f;
    const float sfmax1 = 1.f / sfmin1;
    const float sfmin2 = sfmin1 * sclfac;
    const float sfmax2 = 1.f / sfmin2;
    bool noconv = true;
    while (noconv){
      noconv = false;
      for (int i2 = k; i2 <= l; ++i2){
        float c = 0.f, r = 0.f;
        for (int j = k; j <= l; ++j){
          if (j == i2) continue;
          c += fabsf(A_(j,i2));
          r += fabsf(A_(i2,j));
        }
        float ca = 0.f; for (int rr = 1; rr <= l; ++rr) ca = fmaxf(ca, fabsf(A_(rr,i2)));
        float ra = 0.f; for (int cc = k; cc <= n; ++cc) ra = fmaxf(ra, fabsf(A_(i2,cc)));
        if (c == 0.f || r == 0.f) continue;
        float g = r / sclfac, f = 1.f, s = c + r;
        while (c < g){
          if (fmaxf(fmaxf(f,c),ca) >= sfmax2 || fminf(fminf(r,g),ra) <= sfmin2) break;
          f *= sclfac; c *= sclfac; ca *= sclfac; r /= sclfac; g /= sclfac; ra /= sclfac;
        }
        g = c / sclfac;
        while (g >= r){
          if (fmaxf(r,ra) >= sfmax2 || fminf(fminf(f,c),fminf(g,ca)) <= sfmin2) break;
          f /= sclfac; c /= sclfac; g /= sclfac; ca /= sclfac; r *= sclfac; ra *= sclfac;
        }
        if ((c + r) >= factor*s) continue;
        if (f < 1.f && scl[i2-1] < 1.f){ if (f*scl[i2-1] <= sfmin1) continue; }
        if (f > 1.f && scl[i2-1] > 1.f){ if (scl[i2-1] >= sfmax1/f) continue; }
        float gg = 1.f/f;
        scl[i2-1] *= f;
        noconv = true;
        for (int cc = k; cc <= n; ++cc) A_(i2,cc) *= gg;
        for (int rr = 1; rr <= l; ++rr) A_(rr,i2) *= f;
      }
    }
  }
  const int ilo = k, ihi = l;

  // ---- sgehd2: unblocked Hessenberg reduction on [ilo..ihi] ----
  for (int i2 = ilo; i2 <= ihi-1; ++i2){
    int nv = ihi - i2;    // reflector length
    int xrow = (i2+2 <= n) ? (i2+2) : n;
    float tau = slarfg_col(nv, &A_(i2+1, i2), &A_(xrow, i2));
    float aii = A_(i2+1, i2);
    A_(i2+1, i2) = 1.f;
    if (tau != 0.f){       // sger quick-returns when alpha == 0
      // right: A(1:ihi, i2+1:ihi) = A (I - tau v v^T)
      for (int row = 1; row <= ihi; ++row){
        float w = 0.f;
        for (int c2 = 1; c2 <= nv; ++c2) w += A_(row, i2+c2) * A_(i2+c2, i2);
        for (int c2 = 1; c2 <= nv; ++c2){
          float temp = (-tau) * A_(i2+c2, i2);
          A_(row, i2+c2) += w * temp;
        }
      }
      // left: A(i2+1:ihi, i2+1:n) = (I - tau v v^T) A
      for (int c2 = i2+1; c2 <= n; ++c2){
        float w = 0.f;
        for (int r2 = 1; r2 <= nv; ++r2) w += A_(i2+r2, c2) * A_(i2+r2, i2);
        float temp = (-tau) * w;
        for (int r2 = 1; r2 <= nv; ++r2) A_(i2+r2, c2) += A_(i2+r2, i2) * temp;
      }
    }
    A_(i2+1, i2) = aii;
  }

  // ---- shseqr prefill for gebal-isolated eigenvalues ----
  for (int p = 1; p <= ilo-1; ++p){ WR_(p) = A_(p,p); WI_(p) = 0.f; }
  for (int p = ihi+1; p <= n; ++p){ WR_(p) = A_(p,p); WI_(p) = 0.f; }

  // ---- slahqr (WANTT = WANTZ = false) ----
  if (ilo == ihi){
    WR_(ilo) = A_(ilo, ilo); WI_(ilo) = 0.f;
  } else if (ilo < ihi) {
    for (int j = ilo; j <= ihi-3; ++j){ A_(j+2, j) = 0.f; A_(j+3, j) = 0.f; }
    if (ilo <= ihi-2) A_(ihi, ihi-2) = 0.f;
    const int nh = ihi - ilo + 1;
    const float ulp = 1.1920929e-7f;
    const float smlnum = 1.17549435e-38f * ((float)nh / ulp);
    const int itmax = 30 * (nh > 10 ? nh : 10);
    int kdefl = 0;
    int i = ihi;
    while (i >= ilo){
      int l1 = ilo;
      bool conv = false;
      for (int its = 0; its <= itmax && !conv; ++its){
        // look for a single small subdiagonal (with Ahues-Tisseur criterion)
        int kk;
        for (kk = i; kk >= l1+1; --kk){
          float hk = fabsf(A_(kk, kk-1));
          if (hk <= smlnum) break;
          float tst = fabsf(A_(kk-1,kk-1)) + fabsf(A_(kk,kk));
          if (tst == 0.f){
            if (kk-2 >= ilo) tst += fabsf(A_(kk-1, kk-2));
            if (kk+1 <= ihi) tst += fabsf(A_(kk+1, kk));
          }
          if (hk <= ulp*tst){
            float ab = fmaxf(fabsf(A_(kk,kk-1)), fabsf(A_(kk-1,kk)));
            float ba = fminf(fabsf(A_(kk,kk-1)), fabsf(A_(kk-1,kk)));
            float aa = fmaxf(fabsf(A_(kk,kk)), fabsf(A_(kk-1,kk-1) - A_(kk,kk)));
            float bb = fminf(fabsf(A_(kk,kk)), fabsf(A_(kk-1,kk-1) - A_(kk,kk)));
            float s = aa + ab;
            if (ba*(ab/s) <= fmaxf(smlnum, ulp*(bb*(aa/s)))) break;
          }
        }
        l1 = kk;
        if (l1 > ilo) A_(l1, l1-1) = 0.f;
        if (l1 >= i-1){ conv = true; break; }
        kdefl++;
        // shifts
        float h11,h12,h21,h22;
        if (kdefl % 20 == 0){
          float s = fabsf(A_(i,i-1)) + fabsf(A_(i-1,i-2));
          h11 = 0.75f*s + A_(i,i); h12 = -0.4375f*s; h21 = s; h22 = h11;
        } else if (kdefl % 10 == 0){
          float s = fabsf(A_(l1+1,l1)) + fabsf(A_(l1+2,l1+1));
          h11 = 0.75f*s + A_(l1,l1); h12 = -0.4375f*s; h21 = s; h22 = h11;
        } else {
          h11 = A_(i-1,i-1); h21 = A_(i,i-1); h12 = A_(i-1,i); h22 = A_(i,i);
        }
        float s = fabsf(h11)+fabsf(h12)+fabsf(h21)+fabsf(h22);
        float rt1r, rt1i, rt2r, rt2i;
        if (s == 0.f){ rt1r = rt1i = rt2r = rt2i = 0.f; }
        else {
          h11 /= s; h21 /= s; h12 /= s; h22 /= s;
          float tr = (h11 + h22)/2.f;
          float det = (h11 - tr)*(h22 - tr) - h12*h21;
          float rtdisc = sqrtf(fabsf(det));
          if (det >= 0.f){
            rt1r = tr*s; rt2r = rt1r; rt1i = rtdisc*s; rt2i = -rt1i;
          } else {
            rt1r = tr + rtdisc; rt2r = tr - rtdisc;
            if (fabsf(rt1r - h22) <= fabsf(rt2r - h22)){ rt1r *= s; rt2r = rt1r; }
            else { rt2r *= s; rt1r = rt2r; }
            rt1i = 0.f; rt2i = 0.f;
          }
        }
        // look for two consecutive small subdiagonals
        int m;
        float v1 = 0.f, v2 = 0.f, v3 = 0.f;
        for (m = i-2; m >= l1; --m){
          float h21s = A_(m+1, m);
          float s2 = fabsf(A_(m,m) - rt2r) + fabsf(rt2i) + fabsf(h21s);
          h21s = A_(m+1,m) / s2;
          v1 = h21s*A_(m, m+1) + (A_(m,m) - rt1r)*((A_(m,m) - rt2r)/s2) - rt1i*(rt2i/s2);
          v2 = h21s*(A_(m,m) + A_(m+1,m+1) - rt1r - rt2r);
          v3 = h21s*A_(m+2, m+1);
          float s3 = fabsf(v1) + fabsf(v2) + fabsf(v3);
          v1 /= s3; v2 /= s3; v3 /= s3;
          if (m == l1) break;
          if (fabsf(A_(m, m-1))*(fabsf(v2)+fabsf(v3)) <=
              ulp*fabsf(v1)*(fabsf(A_(m-1,m-1)) + fabsf(A_(m,m)) + fabsf(A_(m+1,m+1)))) break;
        }
        // double-shift QR sweep
        for (int kq = m; kq <= i-1; ++kq){
          int nr = (i - kq + 1 < 3) ? (i - kq + 1) : 3;
          float vv1, vv2, vv3 = 0.f;
          if (kq > m){
            vv1 = A_(kq, kq-1); vv2 = A_(kq+1, kq-1);
            if (nr == 3) vv3 = A_(kq+2, kq-1);
          } else { vv1 = v1; vv2 = v2; vv3 = v3; }
          float t1 = slarfg23(nr, &vv1, &vv2, &vv3);
          if (kq > m){
            A_(kq, kq-1) = vv1;
            A_(kq+1, kq-1) = 0.f;
            if (kq < i-1) A_(kq+2, kq-1) = 0.f;
          } else if (m > l1){
            A_(kq, kq-1) = A_(kq, kq-1)*(1.f - t1);
          }
          float v2r = vv2, t2 = t1*v2r;
          if (nr == 3){
            float v3r = vv3, t3 = t1*v3r;
            for (int j = kq; j <= i; ++j){
              float sum = A_(kq,j) + v2r*A_(kq+1,j) + v3r*A_(kq+2,j);
              A_(kq,j)   -= sum*t1;
              A_(kq+1,j) -= sum*t2;
              A_(kq+2,j) -= sum*t3;
            }
            int jhi = (kq+3 < i) ? (kq+3) : i;
            for (int j = l1; j <= jhi; ++j){
              float sum = t1*A_(j,kq) + t2*A_(j,kq+1) + t3*A_(j,kq+2);
              A_(j,kq)   -= sum;
              A_(j,kq+1) -= sum*v2r;
              A_(j,kq+2) -= sum*v3r;
            }
          } else {
            for (int j = kq; j <= i; ++j){
              float sum = A_(kq,j) + v2r*A_(kq+1,j);
              A_(kq,j)   -= sum*t1;
              A_(kq+1,j) -= sum*t2;
            }
            for (int j = l1; j <= i; ++j){
              float sum = t1*A_(j,kq) + t2*A_(j,kq+1);
              A_(j,kq)   -= sum;
              A_(j,kq+1) -= sum*v2r;
            }
          }
        }
      } // its
      if (l1 == i){
        WR_(i) = A_(i,i); WI_(i) = 0.f;
      } else if (l1 == i-1){
        slanv2f(A_(i-1,i-1), A_(i-1,i), A_(i,i-1), A_(i,i),
                &WR_(i-1), &WI_(i-1), &WR_(i), &WI_(i));
      } else {
        // non-convergence fallback (practically unreachable)
        WR_(i) = A_(i,i); WI_(i) = 0.f;
        l1 = i;
      }
      kdefl = 0;
      i = l1 - 1;
    }
  }
#undef A_
#undef WR_
#undef WI_
}

// ---------------------------------------------------------------------------
// Kernel 0: deg vectors, pattern table (32 true matrices), zero histogram.
// misc layout (floats): [0..4] degP, [5..9] degT,
//                       [10..329] evT[32][5][2], [330..649] qT[32][5][2]
// ---------------------------------------------------------------------------
__global__ __launch_bounds__(64) void eig_init(const float* __restrict__ yt,
                                               const float* __restrict__ yp,
                                               float* __restrict__ misc,
                                               unsigned int* __restrict__ hist)
{
#pragma clang fp contract(off)
  __shared__ float sm[64*STRIDE];
  __shared__ float sdegT[5];
  const int t = threadIdx.x;
  if (t < 32) hist[t] = 0;
  if (t < 5){
    float xp[5], xt[5];
    for (int j = 0; j < 5; ++j){ xp[j] = yp[t*5+j]; xt[j] = yt[t*5+j]; }
    float cs = 0.f;
    for (int i = 0; i < 5; ++i){
      bool ci = (xp[i] != 0.f);
      float base = ci ? xp[t] : (1.f - xp[t]);
      float m2 = 2.f*base - 1.f;
      cs += (i == t) ? 0.f : m2;
    }
    misc[t] = cs - 1.f;                 // degP[t]
    float cs2 = 0.f;
    for (int i = 0; i < 5; ++i){
      bool ci = (xt[i] != 0.f);
      float base = ci ? xt[t] : (1.f - xt[t]);
      float m2 = 2.f*base - 1.f;
      cs2 += (i == t) ? 0.f : m2;
    }
    float dgt = cs2 - 1.f;
    misc[5 + t] = dgt;                  // degT[t]
    sdegT[t] = dgt;
  }
  __syncthreads();
  if (t < 32){
    float* h  = &sm[t*STRIDE];
    float* wr = h + 25;
    float* wi = h + 30;
    float xv[5];
    for (int j = 0; j < 5; ++j) xv[j] = ((t >> j) & 1) ? 1.f : 0.f;
    for (int i = 0; i < 5; ++i){
      bool ci = (xv[i] != 0.f);
      for (int j = 0; j < 5; ++j){
        float base = ci ? xv[j] : (1.f - xv[j]);
        float m2 = 2.f*base - 1.f;
        float adj = (i == j) ? 0.f : m2;
        h[j*5 + i] = sdegT[j] - adj;    // lap_true (column-major)
      }
    }
    sgeev5(h, wr, wi);
    float tr = 0.f, ti = 0.f;
    for (int kx = 0; kx < 5; ++kx){ tr += wr[kx]; ti += wi[kx]; }
    float den = tr*tr + ti*ti;
    float cr = 0.f, cii = 0.f;
    for (int kx = 0; kx < 5; ++kx){
      misc[10 + t*10 + 2*kx]     = wr[kx];
      misc[10 + t*10 + 2*kx + 1] = wi[kx];
      cr += wr[kx]; cii += wi[kx];
      misc[330 + t*10 + 2*kx]     = (cr*tr + cii*ti)/den;
      misc[330 + t*10 + 2*kx + 1] = (cii*tr - cr*ti)/den;
    }
  }
}

// ---------------------------------------------------------------------------
// Kernel 1: per-batch pred eigensolve + accumulate per-block partials.
// partials[block][0..9]  = sum of cums_pred[k]/total_pred (re,im interleaved)
// partials[block][10..14]= sum of |ev_pred[k]-ev_true[k]|^2
// ---------------------------------------------------------------------------
__global__ __launch_bounds__(256) void eig_main(const float* __restrict__ yt,
                                                const float* __restrict__ yp,
                                                double* __restrict__ partials,
                                                unsigned int* __restrict__ hist,
                                                const float* __restrict__ misc,
                                                int nb)
{
#pragma clang fp contract(off)
  __shared__ float sm[256*STRIDE];
  __shared__ double red[4][16];
  __shared__ unsigned int hloc[32];
  const int tid = threadIdx.x;
  const int b = blockIdx.x*256 + tid;
  if (tid < 32) hloc[tid] = 0;
  __syncthreads();

  double vals[15];
  #pragma unroll
  for (int q = 0; q < 15; ++q) vals[q] = 0.0;

  if (b < nb){
    float* h  = &sm[tid*STRIDE];
    float* wr = h + 25;
    float* wi = h + 30;
    float x[5];
    #pragma unroll
    for (int j = 0; j < 5; ++j) x[j] = yp[b*5 + j];
    float degp[5];
    #pragma unroll
    for (int j = 0; j < 5; ++j) degp[j] = misc[j];
    #pragma unroll
    for (int i = 0; i < 5; ++i){
      const bool ci = (x[i] != 0.f);
      #pragma unroll
      for (int j = 0; j < 5; ++j){
        float base = ci ? x[j] : (1.f - x[j]);
        float m2 = 2.f*base - 1.f;
        float adj = (i == j) ? 0.f : m2;
        h[j*5 + i] = degp[j] - adj;     // lap_pred (column-major)
      }
    }
    sgeev5(h, wr, wi);
    float er[5], ei[5];
    #pragma unroll
    for (int kx = 0; kx < 5; ++kx){ er[kx] = wr[kx]; ei[kx] = wi[kx]; }
    float tr = 0.f, ti = 0.f;
    #pragma unroll
    for (int kx = 0; kx < 5; ++kx){ tr += er[kx]; ti += ei[kx]; }
    float den = tr*tr + ti*ti;
    float cr = 0.f, cii = 0.f;
    #pragma unroll
    for (int kx = 0; kx < 5; ++kx){
      cr += er[kx]; cii += ei[kx];
      float qr = (cr*tr + cii*ti)/den;
      float qi = (cii*tr - cr*ti)/den;
      vals[2*kx]   = (double)qr;
      vals[2*kx+1] = (double)qi;
    }
    int p = 0;
    #pragma unroll
    for (int j = 0; j < 5; ++j){ if (yt[b*5 + j] != 0.f) p |= (1 << j); }
    #pragma unroll
    for (int kx = 0; kx < 5; ++kx){
      float dr = er[kx] - misc[10 + p*10 + 2*kx];
      float di = ei[kx] - misc[10 + p*10 + 2*kx + 1];
      vals[10 + kx] = (double)dr*(double)dr + (double)di*(double)di;
    }
    atomicAdd(&hloc[p], 1u);
  }

  const int lane = tid & 63, wid = tid >> 6;
  #pragma unroll
  for (int q = 0; q < 15; ++q){
    double v = vals[q];
    #pragma unroll
    for (int off = 32; off >= 1; off >>= 1) v += __shfl_down(v, off, 64);
    if (lane == 0) red[wid][q] = v;
  }
  __syncthreads();
  if (tid == 0){
    #pragma unroll
    for (int q = 0; q < 15; ++q)
      partials[(size_t)blockIdx.x*15 + q] = red[0][q] + red[1][q] + red[2][q] + red[3][q];
  }
  if (tid < 32){
    unsigned int cv = hloc[tid];
    if (cv) atomicAdd(&hist[tid], cv);
  }
}

// ---------------------------------------------------------------------------
// Kernel 2: reduce partials, energies -> k_pred/k_true -> min_k -> distance.
// ---------------------------------------------------------------------------
__global__ __launch_bounds__(256) void eig_final(const double* __restrict__ partials,
                                                 const unsigned int* __restrict__ hist,
                                                 const float* __restrict__ misc,
                                                 float* __restrict__ out,
                                                 int nb, int nblk)
{
#pragma clang fp contract(off)
  __shared__ double r2[4][16];
  const int tid = threadIdx.x;
  double acc[15];
  #pragma unroll
  for (int q = 0; q < 15; ++q) acc[q] = 0.0;
  for (int ib = tid; ib < nblk; ib += 256){
    #pragma unroll
    for (int q = 0; q < 15; ++q) acc[q] += partials[(size_t)ib*15 + q];
  }
  const int lane = tid & 63, wid = tid >> 6;
  #pragma unroll
  for (int q = 0; q < 15; ++q){
    double v = acc[q];
    #pragma unroll
    for (int off = 32; off >= 1; off >>= 1) v += __shfl_down(v, off, 64);
    if (lane == 0) r2[wid][q] = v;
  }
  __syncthreads();
  if (tid == 0){
    double tot[15];
    for (int q = 0; q < 15; ++q) tot[q] = r2[0][q] + r2[1][q] + r2[2][q] + r2[3][q];
    const double Bd = (double)nb;
    int kp = 5;
    for (int kx = 0; kx < 5; ++kx){
      double re = tot[2*kx]/Bd, im = tot[2*kx+1]/Bd;
      double e = sqrt(re*re + im*im);
      if (e > 0.85){ kp = kx + 1; break; }
    }
    int kt = 5;
    for (int kx = 0; kx < 5; ++kx){
      double re = 0.0, im = 0.0;
      for (int p = 0; p < 32; ++p){
        double cnt = (double)hist[p];
        re += cnt * (double)misc[330 + p*10 + 2*kx];
        im += cnt * (double)misc[330 + p*10 + 2*kx + 1];
      }
      re /= Bd; im /= Bd;
      double e = sqrt(re*re + im*im);
      if (e > 0.85){ kt = kx + 1; break; }
    }
    int mink = (kp < kt) ? kp : kt;
    double d2 = 0.0;
    for (int j = 0; j < mink; ++j) d2 += tot[10 + j];
    out[0] = (float)sqrt(d2);
  }
}

extern "C" void kernel_launch(void* const* d_in, const int* in_sizes, int n_in,
                              void* d_out, int out_size, void* d_ws, size_t ws_size,
                              hipStream_t stream)
{
  const float* yt = (const float*)d_in[0];   // y_true (0/1 floats)
  const float* yp = (const float*)d_in[1];   // y_pred (uniform floats)
  float* out = (float*)d_out;
  const int nb = in_sizes[0] / 5;
  const int nblk = (nb + 255) / 256;

  char* ws = (char*)d_ws;
  double* partials = (double*)ws;                       // nblk*15 doubles
  size_t off = (size_t)nblk * 15 * sizeof(double);
  off = (off + 255) & ~(size_t)255;
  unsigned int* hist = (unsigned int*)(ws + off);       // 32 u32
  float* misc = (float*)(ws + off + 256);               // 650 floats

  eig_init<<<1, 64, 0, stream>>>(yt, yp, misc, hist);
  eig_main<<<nblk, 256, 0, stream>>>(yt, yp, partials, hist, misc, nb);
  eig_final<<<1, 256, 0, stream>>>(partials, hist, misc, out, nb, nblk);
}

// Round 6
// 314.443 us; speedup vs baseline: 1.3369x; 1.3369x over previous
//
#include <hip/hip_runtime.h>
#include <math.h>

// ---------------------------------------------------------------------------
// EigenLoss: faithful re-implementation of the JAX reference, including a
// LAPACK-sgeev-equivalent (sgebal 'B' -> sgehd2 -> slahqr/slanv2) eigenvalue
// solver for 5x5 real matrices (column-major, as jax passes to LAPACK).
//
// R2 changes (unmeasured, resubmitted): transposed LDS layout (zero bank
// conflicts), H-only in LDS (26 KB/block -> 6 blocks/CU), wr/wi/scl in
// registers (switch setters), eig_init parallelized across 32 blocks.
// ---------------------------------------------------------------------------

#define DEV __device__ __forceinline__

static DEV float slapy2f(float x, float y){
#pragma clang fp contract(off)
  float xa = fabsf(x), ya = fabsf(y);
  float w = fmaxf(xa, ya), z = fminf(xa, ya);
  if (z == 0.f) return w;
  float r = z / w;
  return w * sqrtf(1.f + r*r);
}

// LAPACK slarfg on a strided vector (alpha, x[0..n-2]); returns tau.
template<int LS>
static DEV float slarfg_col(int n, float* alpha, float* x){
#pragma clang fp contract(off)
  if (n <= 1) return 0.f;
  int m = n - 1;
  float xnorm;
  if (m == 1) xnorm = fabsf(x[0]);
  else {
    float scl = 0.f, ssq = 1.f;       // reference-BLAS snrm2 (ssq form)
    for (int i = 0; i < m; ++i){
      float xi = x[i*LS];
      if (xi != 0.f){
        float ax = fabsf(xi);
        if (scl < ax){ float r = scl/ax; ssq = 1.f + ssq*(r*r); scl = ax; }
        else         { float r = ax/scl; ssq = ssq + r*r; }
      }
    }
    xnorm = scl * sqrtf(ssq);
  }
  if (xnorm == 0.f) return 0.f;
  float a = *alpha;
  float beta = -copysignf(slapy2f(a, xnorm), a);
  float tau = (beta - a) / beta;
  float sc = 1.f / (a - beta);
  for (int i = 0; i < m; ++i) x[i*LS] *= sc;
  *alpha = beta;
  return tau;
}

// slarfg specialized for the slahqr sweep vectors (nr in {2,3}, registers).
static DEV float slarfg23(int nr, float* alpha, float* x1, float* x2){
#pragma clang fp contract(off)
  float xnorm;
  if (nr == 2) xnorm = fabsf(*x1);
  else {
    float scl = 0.f, ssq = 1.f;
    float v = *x1;
    if (v != 0.f){ float ax = fabsf(v); if (scl < ax){ float r=scl/ax; ssq=1.f+ssq*(r*r); scl=ax; } else { float r=ax/scl; ssq+=r*r; } }
    v = *x2;
    if (v != 0.f){ float ax = fabsf(v); if (scl < ax){ float r=scl/ax; ssq=1.f+ssq*(r*r); scl=ax; } else { float r=ax/scl; ssq+=r*r; } }
    xnorm = scl*sqrtf(ssq);
  }
  if (xnorm == 0.f) return 0.f;
  float a = *alpha;
  float beta = -copysignf(slapy2f(a, xnorm), a);
  float tau = (beta - a)/beta;
  float sc = 1.f/(a - beta);
  *x1 *= sc;
  if (nr == 3) *x2 *= sc;
  *alpha = beta;
  return tau;
}

// LAPACK slanv2 (eigenvalues-only use; rotation outputs dropped).
static DEV void slanv2f(float a, float b, float c, float d,
                        float* rt1r, float* rt1i, float* rt2r, float* rt2i){
#pragma clang fp contract(off)
  const float eps = 1.1920929e-7f;    // slamch('P')
  if (c == 0.f){
    // nothing
  } else if (b == 0.f){
    float t = d; d = a; a = t; b = -c; c = 0.f;
  } else if ((a - d) == 0.f && copysignf(1.f,b) != copysignf(1.f,c)){
    // standardized already
  } else {
    float temp = a - d;
    float p = 0.5f*temp;
    float bcmax = fmaxf(fabsf(b), fabsf(c));
    float bcmis = fminf(fabsf(b), fabsf(c)) * copysignf(1.f,b) * copysignf(1.f,c);
    float scale = fmaxf(fabsf(p), bcmax);
    float z = (p/scale)*p + (bcmax/scale)*bcmis;
    if (z >= 4.f*eps){
      z = p + copysignf(sqrtf(scale)*sqrtf(z), p);
      a = d + z;
      d = d - (bcmax/z)*bcmis;
      b = b - c;
      c = 0.f;
    } else {
      float sigma = b + c;
      float tau = slapy2f(sigma, temp);
      float cs = sqrtf(0.5f*(1.f + fabsf(sigma)/tau));
      float sn = -(p/(tau*cs))*copysignf(1.f, sigma);
      float aa = a*cs + b*sn,  bb = -a*sn + b*cs;
      float cc = c*cs + d*sn,  dd = -c*sn + d*cs;
      a = aa*cs + cc*sn;  b = bb*cs + dd*sn;
      c = -aa*sn + cc*cs; d = -bb*sn + dd*cs;
      temp = 0.5f*(a+d);
      a = temp; d = temp;
      if (c != 0.f){
        if (b != 0.f){
          if (copysignf(1.f,b) == copysignf(1.f,c)){
            float sab = sqrtf(fabsf(b)), sac = sqrtf(fabsf(c));
            p = copysignf(sab*sac, c);
            a = temp + p; d = temp - p;
            b = b - c; c = 0.f;
          }
        } else {
          b = -c; c = 0.f;
        }
      }
    }
  }
  *rt1r = a; *rt2r = d;
  if (c == 0.f){ *rt1i = 0.f; *rt2i = 0.f; }
  else { *rt1i = sqrtf(fabsf(b))*sqrtf(fabsf(c)); *rt2i = -(*rt1i); }
}

// sgeev ('N','N') for a 5x5 column-major matrix; element idx at h[idx*LS].
// Results written to er[0..4]/ei[0..4] (constant-indexed stores -> registers).
template<int LS>
static __device__ void sgeev5(float* __restrict__ h,
                              float* __restrict__ er, float* __restrict__ ei){
#pragma clang fp contract(off)
#define A_(i,j) h[((((j)-1)*5 + ((i)-1)))*LS]
  const int n = 5;
  float wr1=0.f,wr2=0.f,wr3=0.f,wr4=0.f,wr5=0.f;
  float wi1=0.f,wi2=0.f,wi3=0.f,wi4=0.f,wi5=0.f;
  auto SETW = [&](int i, float vr, float vi){
    switch(i){
      case 1: wr1=vr; wi1=vi; break;
      case 2: wr2=vr; wi2=vi; break;
      case 3: wr3=vr; wi3=vi; break;
      case 4: wr4=vr; wi4=vi; break;
      default: wr5=vr; wi5=vi; break;
    }
  };
  float scl1=1.f,scl2=1.f,scl3=1.f,scl4=1.f,scl5=1.f;
  auto SCLGET = [&](int i)->float{
    switch(i){ case 1: return scl1; case 2: return scl2; case 3: return scl3;
               case 4: return scl4; default: return scl5; }
  };
  auto SCLMUL = [&](int i, float f){
    switch(i){ case 1: scl1*=f; break; case 2: scl2*=f; break; case 3: scl3*=f; break;
               case 4: scl4*=f; break; default: scl5*=f; break; }
  };

  int k = 1, l = 5;
  bool balDone = false;

  // ---- sgebal 'B': permutation, row phase (push isolated rows to bottom) ----
  {
    bool again = true;
    while (again){
      again = false;
      for (int j = l; j >= 1; --j){
        bool iso = true;
        for (int i2 = 1; i2 <= l; ++i2){
          if (i2 == j) continue;
          if (A_(j,i2) != 0.f){ iso = false; break; }
        }
        if (iso){
          if (j != l){
            for (int r = 1; r <= l; ++r){ float t = A_(r,j); A_(r,j) = A_(r,l); A_(r,l) = t; }
            for (int c = k; c <= n; ++c){ float t = A_(j,c); A_(j,c) = A_(l,c); A_(l,c) = t; }
          }
          l -= 1;
          if (l == 1) balDone = true;   // netlib: GOTO 210
          else again = true;
          break;
        }
      }
      if (balDone) break;
    }
  }
  if (!balDone){
    // ---- permutation, column phase (push isolated columns to top) ----
    bool again = true;
    while (again){
      again = false;
      for (int j = k; j <= l; ++j){
        bool iso = true;
        for (int i2 = k; i2 <= l; ++i2){
          if (i2 == j) continue;
          if (A_(i2,j) != 0.f){ iso = false; break; }
        }
        if (iso){
          if (j != k){
            for (int r = 1; r <= l; ++r){ float t = A_(r,j); A_(r,j) = A_(r,k); A_(r,k) = t; }
            for (int c = k; c <= n; ++c){ float t = A_(j,c); A_(j,c) = A_(k,c); A_(k,c) = t; }
          }
          k += 1;
          again = true;
          break;
        }
      }
    }
    // ---- iterative power-of-2 scaling ----
    const float sclfac = 2.f, factor = 0.95f;
    const float sfmin1 = 1.17549435e-38f / 1.1920929e-7f;
    const float sfmax1 = 1.f / sfmin1;
    const float sfmin2 = sfmin1 * sclfac;
    const float sfmax2 = 1.f / sfmin2;
    bool noconv = true;
    while (noconv){
      noconv = false;
      for (int i2 = k; i2 <= l; ++i2){
        float c = 0.f, r = 0.f;
        for (int j = k; j <= l; ++j){
          if (j == i2) continue;
          c += fabsf(A_(j,i2));
          r += fabsf(A_(i2,j));
        }
        float ca = 0.f; for (int rr = 1; rr <= l; ++rr) ca = fmaxf(ca, fabsf(A_(rr,i2)));
        float ra = 0.f; for (int cc = k; cc <= n; ++cc) ra = fmaxf(ra, fabsf(A_(i2,cc)));
        if (c == 0.f || r == 0.f) continue;
        float g = r / sclfac, f = 1.f, s = c + r;
        while (c < g){
          if (fmaxf(fmaxf(f,c),ca) >= sfmax2 || fminf(fminf(r,g),ra) <= sfmin2) break;
          f *= sclfac; c *= sclfac; ca *= sclfac; r /= sclfac; g /= sclfac; ra /= sclfac;
        }
        g = c / sclfac;
        while (g >= r){
          if (fmaxf(r,ra) >= sfmax2 || fminf(fminf(f,c),fminf(g,ca)) <= sfmin2) break;
          f /= sclfac; c /= sclfac; g /= sclfac; ca /= sclfac; r *= sclfac; ra *= sclfac;
        }
        if ((c + r) >= factor*s) continue;
        float s0 = SCLGET(i2);
        if (f < 1.f && s0 < 1.f){ if (f*s0 <= sfmin1) continue; }
        if (f > 1.f && s0 > 1.f){ if (s0 >= sfmax1/f) continue; }
        float gg = 1.f/f;
        SCLMUL(i2, f);
        noconv = true;
        for (int cc = k; cc <= n; ++cc) A_(i2,cc) *= gg;
        for (int rr = 1; rr <= l; ++rr) A_(rr,i2) *= f;
      }
    }
  }
  const int ilo = k, ihi = l;

  // ---- sgehd2: unblocked Hessenberg reduction on [ilo..ihi] ----
  for (int i2 = ilo; i2 <= ihi-1; ++i2){
    int nv = ihi - i2;    // reflector length
    int xrow = (i2+2 <= n) ? (i2+2) : n;
    float tau = slarfg_col<LS>(nv, &A_(i2+1, i2), &A_(xrow, i2));
    float aii = A_(i2+1, i2);
    A_(i2+1, i2) = 1.f;
    if (tau != 0.f){       // sger quick-returns when alpha == 0
      // right: A(1:ihi, i2+1:ihi) = A (I - tau v v^T)
      for (int row = 1; row <= ihi; ++row){
        float w = 0.f;
        for (int c2 = 1; c2 <= nv; ++c2) w += A_(row, i2+c2) * A_(i2+c2, i2);
        for (int c2 = 1; c2 <= nv; ++c2){
          float temp = (-tau) * A_(i2+c2, i2);
          A_(row, i2+c2) += w * temp;
        }
      }
      // left: A(i2+1:ihi, i2+1:n) = (I - tau v v^T) A
      for (int c2 = i2+1; c2 <= n; ++c2){
        float w = 0.f;
        for (int r2 = 1; r2 <= nv; ++r2) w += A_(i2+r2, c2) * A_(i2+r2, i2);
        float temp = (-tau) * w;
        for (int r2 = 1; r2 <= nv; ++r2) A_(i2+r2, c2) += A_(i2+r2, i2) * temp;
      }
    }
    A_(i2+1, i2) = aii;
  }

  // ---- shseqr prefill for gebal-isolated eigenvalues ----
  for (int p = 1; p <= ilo-1; ++p) SETW(p, A_(p,p), 0.f);
  for (int p = ihi+1; p <= n; ++p) SETW(p, A_(p,p), 0.f);

  // ---- slahqr (WANTT = WANTZ = false) ----
  if (ilo == ihi){
    SETW(ilo, A_(ilo, ilo), 0.f);
  } else {
    for (int j = ilo; j <= ihi-3; ++j){ A_(j+2, j) = 0.f; A_(j+3, j) = 0.f; }
    if (ilo <= ihi-2) A_(ihi, ihi-2) = 0.f;
    const int nh = ihi - ilo + 1;
    const float ulp = 1.1920929e-7f;
    const float smlnum = 1.17549435e-38f * ((float)nh / ulp);
    const int itmax = 30 * (nh > 10 ? nh : 10);
    int kdefl = 0;
    int i = ihi;
    while (i >= ilo){
      int l1 = ilo;
      bool conv = false;
      for (int its = 0; its <= itmax && !conv; ++its){
        // look for a single small subdiagonal (with Ahues-Tisseur criterion)
        int kk;
        for (kk = i; kk >= l1+1; --kk){
          float hk = fabsf(A_(kk, kk-1));
          if (hk <= smlnum) break;
          float tst = fabsf(A_(kk-1,kk-1)) + fabsf(A_(kk,kk));
          if (tst == 0.f){
            if (kk-2 >= ilo) tst += fabsf(A_(kk-1, kk-2));
            if (kk+1 <= ihi) tst += fabsf(A_(kk+1, kk));
          }
          if (hk <= ulp*tst){
            float ab = fmaxf(fabsf(A_(kk,kk-1)), fabsf(A_(kk-1,kk)));
            float ba = fminf(fabsf(A_(kk,kk-1)), fabsf(A_(kk-1,kk)));
            float aa = fmaxf(fabsf(A_(kk,kk)), fabsf(A_(kk-1,kk-1) - A_(kk,kk)));
            float bb = fminf(fabsf(A_(kk,kk)), fabsf(A_(kk-1,kk-1) - A_(kk,kk)));
            float s = aa + ab;
            if (ba*(ab/s) <= fmaxf(smlnum, ulp*(bb*(aa/s)))) break;
          }
        }
        l1 = kk;
        if (l1 > ilo) A_(l1, l1-1) = 0.f;
        if (l1 >= i-1){ conv = true; break; }
        kdefl++;
        // shifts
        float h11,h12,h21,h22;
        if (kdefl % 20 == 0){
          float s = fabsf(A_(i,i-1)) + fabsf(A_(i-1,i-2));
          h11 = 0.75f*s + A_(i,i); h12 = -0.4375f*s; h21 = s; h22 = h11;
        } else if (kdefl % 10 == 0){
          float s = fabsf(A_(l1+1,l1)) + fabsf(A_(l1+2,l1+1));
          h11 = 0.75f*s + A_(l1,l1); h12 = -0.4375f*s; h21 = s; h22 = h11;
        } else {
          h11 = A_(i-1,i-1); h21 = A_(i,i-1); h12 = A_(i-1,i); h22 = A_(i,i);
        }
        float s = fabsf(h11)+fabsf(h12)+fabsf(h21)+fabsf(h22);
        float rt1r, rt1i, rt2r, rt2i;
        if (s == 0.f){ rt1r = rt1i = rt2r = rt2i = 0.f; }
        else {
          h11 /= s; h21 /= s; h12 /= s; h22 /= s;
          float tr = (h11 + h22)/2.f;
          float det = (h11 - tr)*(h22 - tr) - h12*h21;
          float rtdisc = sqrtf(fabsf(det));
          if (det >= 0.f){
            rt1r = tr*s; rt2r = rt1r; rt1i = rtdisc*s; rt2i = -rt1i;
          } else {
            rt1r = tr + rtdisc; rt2r = tr - rtdisc;
            if (fabsf(rt1r - h22) <= fabsf(rt2r - h22)){ rt1r *= s; rt2r = rt1r; }
            else { rt2r *= s; rt1r = rt2r; }
            rt1i = 0.f; rt2i = 0.f;
          }
        }
        // look for two consecutive small subdiagonals
        int m;
        float v1 = 0.f, v2 = 0.f, v3 = 0.f;
        for (m = i-2; m >= l1; --m){
          float h21s = A_(m+1, m);
          float s2 = fabsf(A_(m,m) - rt2r) + fabsf(rt2i) + fabsf(h21s);
          h21s = A_(m+1,m) / s2;
          v1 = h21s*A_(m, m+1) + (A_(m,m) - rt1r)*((A_(m,m) - rt2r)/s2) - rt1i*(rt2i/s2);
          v2 = h21s*(A_(m,m) + A_(m+1,m+1) - rt1r - rt2r);
          v3 = h21s*A_(m+2, m+1);
          float s3 = fabsf(v1) + fabsf(v2) + fabsf(v3);
          v1 /= s3; v2 /= s3; v3 /= s3;
          if (m == l1) break;
          if (fabsf(A_(m, m-1))*(fabsf(v2)+fabsf(v3)) <=
              ulp*fabsf(v1)*(fabsf(A_(m-1,m-1)) + fabsf(A_(m,m)) + fabsf(A_(m+1,m+1)))) break;
        }
        // double-shift QR sweep
        for (int kq = m; kq <= i-1; ++kq){
          int nr = (i - kq + 1 < 3) ? (i - kq + 1) : 3;
          float vv1, vv2, vv3 = 0.f;
          if (kq > m){
            vv1 = A_(kq, kq-1); vv2 = A_(kq+1, kq-1);
            if (nr == 3) vv3 = A_(kq+2, kq-1);
          } else { vv1 = v1; vv2 = v2; vv3 = v3; }
          float t1 = slarfg23(nr, &vv1, &vv2, &vv3);
          if (kq > m){
            A_(kq, kq-1) = vv1;
            A_(kq+1, kq-1) = 0.f;
            if (kq < i-1) A_(kq+2, kq-1) = 0.f;
          } else if (m > l1){
            A_(kq, kq-1) = A_(kq, kq-1)*(1.f - t1);
          }
          float v2r = vv2, t2 = t1*v2r;
          if (nr == 3){
            float v3r = vv3, t3 = t1*v3r;
            for (int j = kq; j <= i; ++j){
              float sum = A_(kq,j) + v2r*A_(kq+1,j) + v3r*A_(kq+2,j);
              A_(kq,j)   -= sum*t1;
              A_(kq+1,j) -= sum*t2;
              A_(kq+2,j) -= sum*t3;
            }
            int jhi = (kq+3 < i) ? (kq+3) : i;
            for (int j = l1; j <= jhi; ++j){
              float sum = t1*A_(j,kq) + t2*A_(j,kq+1) + t3*A_(j,kq+2);
              A_(j,kq)   -= sum;
              A_(j,kq+1) -= sum*v2r;
              A_(j,kq+2) -= sum*v3r;
            }
          } else {
            for (int j = kq; j <= i; ++j){
              float sum = A_(kq,j) + v2r*A_(kq+1,j);
              A_(kq,j)   -= sum*t1;
              A_(kq+1,j) -= sum*t2;
            }
            for (int j = l1; j <= i; ++j){
              float sum = t1*A_(j,kq) + t2*A_(j,kq+1);
              A_(j,kq)   -= sum;
              A_(j,kq+1) -= sum*v2r;
            }
          }
        }
      } // its
      if (l1 == i){
        SETW(i, A_(i,i), 0.f);
      } else if (l1 == i-1){
        float r1r,r1i,r2r,r2i;
        slanv2f(A_(i-1,i-1), A_(i-1,i), A_(i,i-1), A_(i,i),
                &r1r, &r1i, &r2r, &r2i);
        SETW(i-1, r1r, r1i);
        SETW(i,   r2r, r2i);
      } else {
        // non-convergence fallback (practically unreachable)
        SETW(i, A_(i,i), 0.f);
        l1 = i;
      }
      kdefl = 0;
      i = l1 - 1;
    }
  }
  er[0]=wr1; er[1]=wr2; er[2]=wr3; er[3]=wr4; er[4]=wr5;
  ei[0]=wi1; ei[1]=wi2; ei[2]=wi3; ei[3]=wi4; ei[4]=wi5;
#undef A_
}

// ---------------------------------------------------------------------------
// Kernel 0 (32 blocks): block 0 computes deg vectors + zeroes hist; each
// block solves its pattern's lap_true and writes the evT/qT tables.
// misc layout (floats): [0..4] degP, [5..9] degT,
//                       [10..329] evT[32][5][2], [330..649] qT[32][5][2]
// ---------------------------------------------------------------------------
__global__ __launch_bounds__(64) void eig_init(const float* __restrict__ yt,
                                               const float* __restrict__ yp,
                                               float* __restrict__ misc,
                                               unsigned int* __restrict__ hist)
{
#pragma clang fp contract(off)
  __shared__ float sm[25];
  const int t = threadIdx.x;
  const int pat = blockIdx.x;
  if (pat == 0){
    if (t < 32) hist[t] = 0;
    if (t < 5){
      float xp[5], xt[5];
      for (int j = 0; j < 5; ++j){ xp[j] = yp[t*5+j]; xt[j] = yt[t*5+j]; }
      float cs = 0.f;
      for (int i = 0; i < 5; ++i){
        bool ci = (xp[i] != 0.f);
        float base = ci ? xp[t] : (1.f - xp[t]);
        float m2 = 2.f*base - 1.f;
        cs += (i == t) ? 0.f : m2;
      }
      misc[t] = cs - 1.f;                 // degP[t]
      float cs2 = 0.f;
      for (int i = 0; i < 5; ++i){
        bool ci = (xt[i] != 0.f);
        float base = ci ? xt[t] : (1.f - xt[t]);
        float m2 = 2.f*base - 1.f;
        cs2 += (i == t) ? 0.f : m2;
      }
      misc[5 + t] = cs2 - 1.f;            // degT[t]
    }
  }
  if (t == 0){
    // recompute degT locally (no cross-block dependency)
    float degT[5];
    #pragma unroll
    for (int r = 0; r < 5; ++r){
      float xr[5];
      #pragma unroll
      for (int j = 0; j < 5; ++j) xr[j] = yt[r*5+j];
      float cs2 = 0.f;
      #pragma unroll
      for (int i = 0; i < 5; ++i){
        bool ci = (xr[i] != 0.f);
        float base = ci ? xr[r] : (1.f - xr[r]);
        float m2 = 2.f*base - 1.f;
        cs2 += (i == r) ? 0.f : m2;
      }
      degT[r] = cs2 - 1.f;
    }
    float xv[5];
    #pragma unroll
    for (int j = 0; j < 5; ++j) xv[j] = ((pat >> j) & 1) ? 1.f : 0.f;
    #pragma unroll
    for (int i = 0; i < 5; ++i){
      bool ci = (xv[i] != 0.f);
      #pragma unroll
      for (int j = 0; j < 5; ++j){
        float base = ci ? xv[j] : (1.f - xv[j]);
        float m2 = 2.f*base - 1.f;
        float adj = (i == j) ? 0.f : m2;
        sm[j*5 + i] = degT[j] - adj;      // lap_true (column-major)
      }
    }
    float er[5], ei[5];
    sgeev5<1>(sm, er, ei);
    float tr = 0.f, ti = 0.f;
    #pragma unroll
    for (int kx = 0; kx < 5; ++kx){ tr += er[kx]; ti += ei[kx]; }
    float den = tr*tr + ti*ti;
    float cr = 0.f, cii = 0.f;
    #pragma unroll
    for (int kx = 0; kx < 5; ++kx){
      misc[10 + pat*10 + 2*kx]     = er[kx];
      misc[10 + pat*10 + 2*kx + 1] = ei[kx];
      cr += er[kx]; cii += ei[kx];
      misc[330 + pat*10 + 2*kx]     = (cr*tr + cii*ti)/den;
      misc[330 + pat*10 + 2*kx + 1] = (cii*tr - cr*ti)/den;
    }
  }
}

// ---------------------------------------------------------------------------
// Kernel 1: per-batch pred eigensolve + accumulate per-block partials.
// LDS: H transposed [25][256] -> bank = tid%32 always (zero conflicts).
// partials[block][0..9]  = sum of cums_pred[k]/total_pred (re,im interleaved)
// partials[block][10..14]= sum of |ev_pred[k]-ev_true[k]|^2
// ---------------------------------------------------------------------------
__global__ __launch_bounds__(256, 6) void eig_main(const float* __restrict__ yt,
                                                   const float* __restrict__ yp,
                                                   double* __restrict__ partials,
                                                   unsigned int* __restrict__ hist,
                                                   const float* __restrict__ misc,
                                                   int nb)
{
#pragma clang fp contract(off)
  __shared__ float sm[25*256];
  __shared__ double red[4][16];
  __shared__ unsigned int hloc[32];
  const int tid = threadIdx.x;
  const int b = blockIdx.x*256 + tid;
  if (tid < 32) hloc[tid] = 0;
  __syncthreads();

  double vals[15];
  #pragma unroll
  for (int q = 0; q < 15; ++q) vals[q] = 0.0;

  if (b < nb){
    float* h = &sm[tid];                 // element idx at h[idx*256]
    float x[5];
    #pragma unroll
    for (int j = 0; j < 5; ++j) x[j] = yp[b*5 + j];
    float degp[5];
    #pragma unroll
    for (int j = 0; j < 5; ++j) degp[j] = misc[j];
    #pragma unroll
    for (int i = 0; i < 5; ++i){
      const bool ci = (x[i] != 0.f);
      #pragma unroll
      for (int j = 0; j < 5; ++j){
        float base = ci ? x[j] : (1.f - x[j]);
        float m2 = 2.f*base - 1.f;
        float adj = (i == j) ? 0.f : m2;
        h[(j*5 + i)*256] = degp[j] - adj; // lap_pred (column-major)
      }
    }
    float er[5], ei[5];
    sgeev5<256>(h, er, ei);
    float tr = 0.f, ti = 0.f;
    #pragma unroll
    for (int kx = 0; kx < 5; ++kx){ tr += er[kx]; ti += ei[kx]; }
    float den = tr*tr + ti*ti;
    float cr = 0.f, cii = 0.f;
    #pragma unroll
    for (int kx = 0; kx < 5; ++kx){
      cr += er[kx]; cii += ei[kx];
      float qr = (cr*tr + cii*ti)/den;
      float qi = (cii*tr - cr*ti)/den;
      vals[2*kx]   = (double)qr;
      vals[2*kx+1] = (double)qi;
    }
    int p = 0;
    #pragma unroll
    for (int j = 0; j < 5; ++j){ if (yt[b*5 + j] != 0.f) p |= (1 << j); }
    #pragma unroll
    for (int kx = 0; kx < 5; ++kx){
      float dr = er[kx] - misc[10 + p*10 + 2*kx];
      float di = ei[kx] - misc[10 + p*10 + 2*kx + 1];
      vals[10 + kx] = (double)dr*(double)dr + (double)di*(double)di;
    }
    atomicAdd(&hloc[p], 1u);
  }

  const int lane = tid & 63, wid = tid >> 6;
  #pragma unroll
  for (int q = 0; q < 15; ++q){
    double v = vals[q];
    #pragma unroll
    for (int off = 32; off >= 1; off >>= 1) v += __shfl_down(v, off, 64);
    if (lane == 0) red[wid][q] = v;
  }
  __syncthreads();
  if (tid == 0){
    #pragma unroll
    for (int q = 0; q < 15; ++q)
      partials[(size_t)blockIdx.x*15 + q] = red[0][q] + red[1][q] + red[2][q] + red[3][q];
  }
  if (tid < 32){
    unsigned int cv = hloc[tid];
    if (cv) atomicAdd(&hist[tid], cv);
  }
}

// ---------------------------------------------------------------------------
// Kernel 2: reduce partials, energies -> k_pred/k_true -> min_k -> distance.
// ---------------------------------------------------------------------------
__global__ __launch_bounds__(256) void eig_final(const double* __restrict__ partials,
                                                 const unsigned int* __restrict__ hist,
                                                 const float* __restrict__ misc,
                                                 float* __restrict__ out,
                                                 int nb, int nblk)
{
#pragma clang fp contract(off)
  __shared__ double r2[4][16];
  const int tid = threadIdx.x;
  double acc[15];
  #pragma unroll
  for (int q = 0; q < 15; ++q) acc[q] = 0.0;
  for (int ib = tid; ib < nblk; ib += 256){
    #pragma unroll
    for (int q = 0; q < 15; ++q) acc[q] += partials[(size_t)ib*15 + q];
  }
  const int lane = tid & 63, wid = tid >> 6;
  #pragma unroll
  for (int q = 0; q < 15; ++q){
    double v = acc[q];
    #pragma unroll
    for (int off = 32; off >= 1; off >>= 1) v += __shfl_down(v, off, 64);
    if (lane == 0) r2[wid][q] = v;
  }
  __syncthreads();
  if (tid == 0){
    double tot[15];
    for (int q = 0; q < 15; ++q) tot[q] = r2[0][q] + r2[1][q] + r2[2][q] + r2[3][q];
    const double Bd = (double)nb;
    int kp = 5;
    for (int kx = 0; kx < 5; ++kx){
      double re = tot[2*kx]/Bd, im = tot[2*kx+1]/Bd;
      double e = sqrt(re*re + im*im);
      if (e > 0.85){ kp = kx + 1; break; }
    }
    int kt = 5;
    for (int kx = 0; kx < 5; ++kx){
      double re = 0.0, im = 0.0;
      for (int p = 0; p < 32; ++p){
        double cnt = (double)hist[p];
        re += cnt * (double)misc[330 + p*10 + 2*kx];
        im += cnt * (double)misc[330 + p*10 + 2*kx + 1];
      }
      re /= Bd; im /= Bd;
      double e = sqrt(re*re + im*im);
      if (e > 0.85){ kt = kx + 1; break; }
    }
    int mink = (kp < kt) ? kp : kt;
    double d2 = 0.0;
    for (int j = 0; j < mink; ++j) d2 += tot[10 + j];
    out[0] = (float)sqrt(d2);
  }
}

extern "C" void kernel_launch(void* const* d_in, const int* in_sizes, int n_in,
                              void* d_out, int out_size, void* d_ws, size_t ws_size,
                              hipStream_t stream)
{
  const float* yt = (const float*)d_in[0];   // y_true (0/1 floats)
  const float* yp = (const float*)d_in[1];   // y_pred (uniform floats)
  float* out = (float*)d_out;
  const int nb = in_sizes[0] / 5;
  const int nblk = (nb + 255) / 256;

  char* ws = (char*)d_ws;
  double* partials = (double*)ws;                       // nblk*15 doubles
  size_t off = (size_t)nblk * 15 * sizeof(double);
  off = (off + 255) & ~(size_t)255;
  unsigned int* hist = (unsigned int*)(ws + off);       // 32 u32
  float* misc = (float*)(ws + off + 256);               // 650 floats

  eig_init<<<32, 64, 0, stream>>>(yt, yp, misc, hist);
  eig_main<<<nblk, 256, 0, stream>>>(yt, yp, partials, hist, misc, nb);
  eig_final<<<1, 256, 0, stream>>>(partials, hist, misc, out, nb, nblk);
}

// Round 7
// 303.610 us; speedup vs baseline: 1.3846x; 1.0357x over previous
//
#include <hip/hip_runtime.h>
#include <math.h>

// ---------------------------------------------------------------------------
// EigenLoss: faithful re-implementation of the JAX reference, including a
// LAPACK-sgeev-equivalent (sgebal 'B' -> sgehd2 -> slahqr/slanv2) eigenvalue
// solver for 5x5 real matrices (column-major, as jax passes to LAPACK).
//
// R6 changes: kill scratch spill (69.6 MB/dispatch of writes at R6 bench).
//  - eigenvalues stored into DEAD cells of H in LDS (rows below the active
//    deflation window are never touched again): real->A_(p,1), imag->A_(p,2).
//  - no more SETW/scl lambdas (reference captures forced an alloca->scratch);
//    scl uses explicit select chains.
//  - sgeev5 __forceinline__, takes only h.
// ---------------------------------------------------------------------------

#define DEV __device__ __forceinline__

static DEV float slapy2f(float x, float y){
#pragma clang fp contract(off)
  float xa = fabsf(x), ya = fabsf(y);
  float w = fmaxf(xa, ya), z = fminf(xa, ya);
  if (z == 0.f) return w;
  float r = z / w;
  return w * sqrtf(1.f + r*r);
}

// LAPACK slarfg on a strided vector (alpha, x[0..n-2]); returns tau.
template<int LS>
static DEV float slarfg_col(int n, float* alpha, float* x){
#pragma clang fp contract(off)
  if (n <= 1) return 0.f;
  int m = n - 1;
  float xnorm;
  if (m == 1) xnorm = fabsf(x[0]);
  else {
    float scl = 0.f, ssq = 1.f;       // reference-BLAS snrm2 (ssq form)
    for (int i = 0; i < m; ++i){
      float xi = x[i*LS];
      if (xi != 0.f){
        float ax = fabsf(xi);
        if (scl < ax){ float r = scl/ax; ssq = 1.f + ssq*(r*r); scl = ax; }
        else         { float r = ax/scl; ssq = ssq + r*r; }
      }
    }
    xnorm = scl * sqrtf(ssq);
  }
  if (xnorm == 0.f) return 0.f;
  float a = *alpha;
  float beta = -copysignf(slapy2f(a, xnorm), a);
  float tau = (beta - a) / beta;
  float sc = 1.f / (a - beta);
  for (int i = 0; i < m; ++i) x[i*LS] *= sc;
  *alpha = beta;
  return tau;
}

// slarfg specialized for the slahqr sweep vectors (nr in {2,3}, registers).
static DEV float slarfg23(int nr, float* alpha, float* x1, float* x2){
#pragma clang fp contract(off)
  float xnorm;
  if (nr == 2) xnorm = fabsf(*x1);
  else {
    float scl = 0.f, ssq = 1.f;
    float v = *x1;
    if (v != 0.f){ float ax = fabsf(v); if (scl < ax){ float r=scl/ax; ssq=1.f+ssq*(r*r); scl=ax; } else { float r=ax/scl; ssq+=r*r; } }
    v = *x2;
    if (v != 0.f){ float ax = fabsf(v); if (scl < ax){ float r=scl/ax; ssq=1.f+ssq*(r*r); scl=ax; } else { float r=ax/scl; ssq+=r*r; } }
    xnorm = scl*sqrtf(ssq);
  }
  if (xnorm == 0.f) return 0.f;
  float a = *alpha;
  float beta = -copysignf(slapy2f(a, xnorm), a);
  float tau = (beta - a)/beta;
  float sc = 1.f/(a - beta);
  *x1 *= sc;
  if (nr == 3) *x2 *= sc;
  *alpha = beta;
  return tau;
}

// LAPACK slanv2 (eigenvalues-only use; rotation outputs dropped).
static DEV void slanv2f(float a, float b, float c, float d,
                        float* rt1r, float* rt1i, float* rt2r, float* rt2i){
#pragma clang fp contract(off)
  const float eps = 1.1920929e-7f;    // slamch('P')
  if (c == 0.f){
    // nothing
  } else if (b == 0.f){
    float t = d; d = a; a = t; b = -c; c = 0.f;
  } else if ((a - d) == 0.f && copysignf(1.f,b) != copysignf(1.f,c)){
    // standardized already
  } else {
    float temp = a - d;
    float p = 0.5f*temp;
    float bcmax = fmaxf(fabsf(b), fabsf(c));
    float bcmis = fminf(fabsf(b), fabsf(c)) * copysignf(1.f,b) * copysignf(1.f,c);
    float scale = fmaxf(fabsf(p), bcmax);
    float z = (p/scale)*p + (bcmax/scale)*bcmis;
    if (z >= 4.f*eps){
      z = p + copysignf(sqrtf(scale)*sqrtf(z), p);
      a = d + z;
      d = d - (bcmax/z)*bcmis;
      b = b - c;
      c = 0.f;
    } else {
      float sigma = b + c;
      float tau = slapy2f(sigma, temp);
      float cs = sqrtf(0.5f*(1.f + fabsf(sigma)/tau));
      float sn = -(p/(tau*cs))*copysignf(1.f, sigma);
      float aa = a*cs + b*sn,  bb = -a*sn + b*cs;
      float cc = c*cs + d*sn,  dd = -c*sn + d*cs;
      a = aa*cs + cc*sn;  b = bb*cs + dd*sn;
      c = -aa*sn + cc*cs; d = -bb*sn + dd*cs;
      temp = 0.5f*(a+d);
      a = temp; d = temp;
      if (c != 0.f){
        if (b != 0.f){
          if (copysignf(1.f,b) == copysignf(1.f,c)){
            float sab = sqrtf(fabsf(b)), sac = sqrtf(fabsf(c));
            p = copysignf(sab*sac, c);
            a = temp + p; d = temp - p;
            b = b - c; c = 0.f;
          }
        } else {
          b = -c; c = 0.f;
        }
      }
    }
  }
  *rt1r = a; *rt2r = d;
  if (c == 0.f){ *rt1i = 0.f; *rt2i = 0.f; }
  else { *rt1i = sqrtf(fabsf(b))*sqrtf(fabsf(c)); *rt2i = -(*rt1i); }
}

// sgeev ('N','N') for a 5x5 column-major matrix; element idx at h[idx*LS].
// On return, eigenvalue p (1-based): real in A_(p,1)=h[(p-1)*LS],
// imag in A_(p,2)=h[(5+p-1)*LS]. These cells are dead by the time they are
// written (rows below the active deflation window are never touched again).
template<int LS>
static DEV void sgeev5(float* __restrict__ h){
#pragma clang fp contract(off)
#define A_(i,j) h[((((j)-1)*5 + ((i)-1)))*LS]
#define SETEV(p, vr, vi) do { int p_ = (p); float vr_ = (vr), vi_ = (vi); \
    h[(p_-1)*LS] = vr_; h[(5 + p_-1)*LS] = vi_; } while(0)
  const int n = 5;
  float scl1=1.f,scl2=1.f,scl3=1.f,scl4=1.f,scl5=1.f;

  int k = 1, l = 5;
  bool balDone = false;

  // ---- sgebal 'B': permutation, row phase (push isolated rows to bottom) ----
  {
    bool again = true;
    while (again){
      again = false;
      for (int j = l; j >= 1; --j){
        bool iso = true;
        for (int i2 = 1; i2 <= l; ++i2){
          if (i2 == j) continue;
          if (A_(j,i2) != 0.f){ iso = false; break; }
        }
        if (iso){
          if (j != l){
            for (int r = 1; r <= l; ++r){ float t = A_(r,j); A_(r,j) = A_(r,l); A_(r,l) = t; }
            for (int c = k; c <= n; ++c){ float t = A_(j,c); A_(j,c) = A_(l,c); A_(l,c) = t; }
          }
          l -= 1;
          if (l == 1) balDone = true;   // netlib: GOTO 210
          else again = true;
          break;
        }
      }
      if (balDone) break;
    }
  }
  if (!balDone){
    // ---- permutation, column phase (push isolated columns to top) ----
    bool again = true;
    while (again){
      again = false;
      for (int j = k; j <= l; ++j){
        bool iso = true;
        for (int i2 = k; i2 <= l; ++i2){
          if (i2 == j) continue;
          if (A_(i2,j) != 0.f){ iso = false; break; }
        }
        if (iso){
          if (j != k){
            for (int r = 1; r <= l; ++r){ float t = A_(r,j); A_(r,j) = A_(r,k); A_(r,k) = t; }
            for (int c = k; c <= n; ++c){ float t = A_(j,c); A_(j,c) = A_(k,c); A_(k,c) = t; }
          }
          k += 1;
          again = true;
          break;
        }
      }
    }
    // ---- iterative power-of-2 scaling ----
    const float sclfac = 2.f, factor = 0.95f;
    const float sfmin1 = 1.17549435e-38f / 1.1920929e-7f;
    const float sfmax1 = 1.f / sfmin1;
    const float sfmin2 = sfmin1 * sclfac;
    const float sfmax2 = 1.f / sfmin2;
    bool noconv = true;
    while (noconv){
      noconv = false;
      for (int i2 = k; i2 <= l; ++i2){
        float c = 0.f, r = 0.f;
        for (int j = k; j <= l; ++j){
          if (j == i2) continue;
          c += fabsf(A_(j,i2));
          r += fabsf(A_(i2,j));
        }
        float ca = 0.f; for (int rr = 1; rr <= l; ++rr) ca = fmaxf(ca, fabsf(A_(rr,i2)));
        float ra = 0.f; for (int cc = k; cc <= n; ++cc) ra = fmaxf(ra, fabsf(A_(i2,cc)));
        if (c == 0.f || r == 0.f) continue;
        float g = r / sclfac, f = 1.f, s = c + r;
        while (c < g){
          if (fmaxf(fmaxf(f,c),ca) >= sfmax2 || fminf(fminf(r,g),ra) <= sfmin2) break;
          f *= sclfac; c *= sclfac; ca *= sclfac; r /= sclfac; g /= sclfac; ra /= sclfac;
        }
        g = c / sclfac;
        while (g >= r){
          if (fmaxf(r,ra) >= sfmax2 || fminf(fminf(f,c),fminf(g,ca)) <= sfmin2) break;
          f /= sclfac; c /= sclfac; g /= sclfac; ca /= sclfac; r *= sclfac; ra *= sclfac;
        }
        if ((c + r) >= factor*s) continue;
        float s0 = (i2==1)?scl1:(i2==2)?scl2:(i2==3)?scl3:(i2==4)?scl4:scl5;
        if (f < 1.f && s0 < 1.f){ if (f*s0 <= sfmin1) continue; }
        if (f > 1.f && s0 > 1.f){ if (s0 >= sfmax1/f) continue; }
        float gg = 1.f/f;
        if      (i2==1) scl1 *= f;
        else if (i2==2) scl2 *= f;
        else if (i2==3) scl3 *= f;
        else if (i2==4) scl4 *= f;
        else            scl5 *= f;
        noconv = true;
        for (int cc = k; cc <= n; ++cc) A_(i2,cc) *= gg;
        for (int rr = 1; rr <= l; ++rr) A_(rr,i2) *= f;
      }
    }
  }
  const int ilo = k, ihi = l;

  // ---- sgehd2: unblocked Hessenberg reduction on [ilo..ihi] ----
  for (int i2 = ilo; i2 <= ihi-1; ++i2){
    int nv = ihi - i2;    // reflector length
    int xrow = (i2+2 <= n) ? (i2+2) : n;
    float tau = slarfg_col<LS>(nv, &A_(i2+1, i2), &A_(xrow, i2));
    float aii = A_(i2+1, i2);
    A_(i2+1, i2) = 1.f;
    if (tau != 0.f){       // sger quick-returns when alpha == 0
      // right: A(1:ihi, i2+1:ihi) = A (I - tau v v^T)
      for (int row = 1; row <= ihi; ++row){
        float w = 0.f;
        for (int c2 = 1; c2 <= nv; ++c2) w += A_(row, i2+c2) * A_(i2+c2, i2);
        for (int c2 = 1; c2 <= nv; ++c2){
          float temp = (-tau) * A_(i2+c2, i2);
          A_(row, i2+c2) += w * temp;
        }
      }
      // left: A(i2+1:ihi, i2+1:n) = (I - tau v v^T) A
      for (int c2 = i2+1; c2 <= n; ++c2){
        float w = 0.f;
        for (int r2 = 1; r2 <= nv; ++r2) w += A_(i2+r2, c2) * A_(i2+r2, i2);
        float temp = (-tau) * w;
        for (int r2 = 1; r2 <= nv; ++r2) A_(i2+r2, c2) += A_(i2+r2, i2) * temp;
      }
    }
    A_(i2+1, i2) = aii;
  }

  // ---- shseqr prefill for gebal-isolated eigenvalues ----
  // Rows < ilo and > ihi are never touched by slahqr below.
  for (int p = 1; p <= ilo-1; ++p){ float v = A_(p,p); SETEV(p, v, 0.f); }
  for (int p = ihi+1; p <= n; ++p){ float v = A_(p,p); SETEV(p, v, 0.f); }

  // ---- slahqr (WANTT = WANTZ = false) ----
  if (ilo == ihi){
    float v = A_(ilo, ilo);
    SETEV(ilo, v, 0.f);
  } else {
    for (int j = ilo; j <= ihi-3; ++j){ A_(j+2, j) = 0.f; A_(j+3, j) = 0.f; }
    if (ilo <= ihi-2) A_(ihi, ihi-2) = 0.f;
    const int nh = ihi - ilo + 1;
    const float ulp = 1.1920929e-7f;
    const float smlnum = 1.17549435e-38f * ((float)nh / ulp);
    const int itmax = 30 * (nh > 10 ? nh : 10);
    int kdefl = 0;
    int i = ihi;
    while (i >= ilo){
      int l1 = ilo;
      bool conv = false;
      for (int its = 0; its <= itmax && !conv; ++its){
        // look for a single small subdiagonal (with Ahues-Tisseur criterion)
        int kk;
        for (kk = i; kk >= l1+1; --kk){
          float hk = fabsf(A_(kk, kk-1));
          if (hk <= smlnum) break;
          float tst = fabsf(A_(kk-1,kk-1)) + fabsf(A_(kk,kk));
          if (tst == 0.f){
            if (kk-2 >= ilo) tst += fabsf(A_(kk-1, kk-2));
            if (kk+1 <= ihi) tst += fabsf(A_(kk+1, kk));
          }
          if (hk <= ulp*tst){
            float ab = fmaxf(fabsf(A_(kk,kk-1)), fabsf(A_(kk-1,kk)));
            float ba = fminf(fabsf(A_(kk,kk-1)), fabsf(A_(kk-1,kk)));
            float aa = fmaxf(fabsf(A_(kk,kk)), fabsf(A_(kk-1,kk-1) - A_(kk,kk)));
            float bb = fminf(fabsf(A_(kk,kk)), fabsf(A_(kk-1,kk-1) - A_(kk,kk)));
            float s = aa + ab;
            if (ba*(ab/s) <= fmaxf(smlnum, ulp*(bb*(aa/s)))) break;
          }
        }
        l1 = kk;
        if (l1 > ilo) A_(l1, l1-1) = 0.f;
        if (l1 >= i-1){ conv = true; break; }
        kdefl++;
        // shifts
        float h11,h12,h21,h22;
        if (kdefl % 20 == 0){
          float s = fabsf(A_(i,i-1)) + fabsf(A_(i-1,i-2));
          h11 = 0.75f*s + A_(i,i); h12 = -0.4375f*s; h21 = s; h22 = h11;
        } else if (kdefl % 10 == 0){
          float s = fabsf(A_(l1+1,l1)) + fabsf(A_(l1+2,l1+1));
          h11 = 0.75f*s + A_(l1,l1); h12 = -0.4375f*s; h21 = s; h22 = h11;
        } else {
          h11 = A_(i-1,i-1); h21 = A_(i,i-1); h12 = A_(i-1,i); h22 = A_(i,i);
        }
        float s = fabsf(h11)+fabsf(h12)+fabsf(h21)+fabsf(h22);
        float rt1r, rt1i, rt2r, rt2i;
        if (s == 0.f){ rt1r = rt1i = rt2r = rt2i = 0.f; }
        else {
          h11 /= s; h21 /= s; h12 /= s; h22 /= s;
          float tr = (h11 + h22)/2.f;
          float det = (h11 - tr)*(h22 - tr) - h12*h21;
          float rtdisc = sqrtf(fabsf(det));
          if (det >= 0.f){
            rt1r = tr*s; rt2r = rt1r; rt1i = rtdisc*s; rt2i = -rt1i;
          } else {
            rt1r = tr + rtdisc; rt2r = tr - rtdisc;
            if (fabsf(rt1r - h22) <= fabsf(rt2r - h22)){ rt1r *= s; rt2r = rt1r; }
            else { rt2r *= s; rt1r = rt2r; }
            rt1i = 0.f; rt2i = 0.f;
          }
        }
        // look for two consecutive small subdiagonals
        int m;
        float v1 = 0.f, v2 = 0.f, v3 = 0.f;
        for (m = i-2; m >= l1; --m){
          float h21s = A_(m+1, m);
          float s2 = fabsf(A_(m,m) - rt2r) + fabsf(rt2i) + fabsf(h21s);
          h21s = A_(m+1,m) / s2;
          v1 = h21s*A_(m, m+1) + (A_(m,m) - rt1r)*((A_(m,m) - rt2r)/s2) - rt1i*(rt2i/s2);
          v2 = h21s*(A_(m,m) + A_(m+1,m+1) - rt1r - rt2r);
          v3 = h21s*A_(m+2, m+1);
          float s3 = fabsf(v1) + fabsf(v2) + fabsf(v3);
          v1 /= s3; v2 /= s3; v3 /= s3;
          if (m == l1) break;
          if (fabsf(A_(m, m-1))*(fabsf(v2)+fabsf(v3)) <=
              ulp*fabsf(v1)*(fabsf(A_(m-1,m-1)) + fabsf(A_(m,m)) + fabsf(A_(m+1,m+1)))) break;
        }
        // double-shift QR sweep
        for (int kq = m; kq <= i-1; ++kq){
          int nr = (i - kq + 1 < 3) ? (i - kq + 1) : 3;
          float vv1, vv2, vv3 = 0.f;
          if (kq > m){
            vv1 = A_(kq, kq-1); vv2 = A_(kq+1, kq-1);
            if (nr == 3) vv3 = A_(kq+2, kq-1);
          } else { vv1 = v1; vv2 = v2; vv3 = v3; }
          float t1 = slarfg23(nr, &vv1, &vv2, &vv3);
          if (kq > m){
            A_(kq, kq-1) = vv1;
            A_(kq+1, kq-1) = 0.f;
            if (kq < i-1) A_(kq+2, kq-1) = 0.f;
          } else if (m > l1){
            A_(kq, kq-1) = A_(kq, kq-1)*(1.f - t1);
          }
          float v2r = vv2, t2 = t1*v2r;
          if (nr == 3){
            float v3r = vv3, t3 = t1*v3r;
            for (int j = kq; j <= i; ++j){
              float sum = A_(kq,j) + v2r*A_(kq+1,j) + v3r*A_(kq+2,j);
              A_(kq,j)   -= sum*t1;
              A_(kq+1,j) -= sum*t2;
              A_(kq+2,j) -= sum*t3;
            }
            int jhi = (kq+3 < i) ? (kq+3) : i;
            for (int j = l1; j <= jhi; ++j){
              float sum = t1*A_(j,kq) + t2*A_(j,kq+1) + t3*A_(j,kq+2);
              A_(j,kq)   -= sum;
              A_(j,kq+1) -= sum*v2r;
              A_(j,kq+2) -= sum*v3r;
            }
          } else {
            for (int j = kq; j <= i; ++j){
              float sum = A_(kq,j) + v2r*A_(kq+1,j);
              A_(kq,j)   -= sum*t1;
              A_(kq+1,j) -= sum*t2;
            }
            for (int j = l1; j <= i; ++j){
              float sum = t1*A_(j,kq) + t2*A_(j,kq+1);
              A_(j,kq)   -= sum;
              A_(j,kq+1) -= sum*v2r;
            }
          }
        }
      } // its
      if (l1 == i){
        float v = A_(i,i);                       // read before overwrite
        SETEV(i, v, 0.f);
      } else if (l1 == i-1){
        float a11 = A_(i-1,i-1), a12 = A_(i-1,i);
        float a21 = A_(i,i-1),   a22 = A_(i,i);  // read all 4 before writes
        float r1r,r1i,r2r,r2i;
        slanv2f(a11, a12, a21, a22, &r1r, &r1i, &r2r, &r2i);
        SETEV(i-1, r1r, r1i);
        SETEV(i,   r2r, r2i);
      } else {
        // non-convergence fallback (practically unreachable)
        float v = A_(i,i);
        SETEV(i, v, 0.f);
        l1 = i;
      }
      kdefl = 0;
      i = l1 - 1;
    }
  }
#undef SETEV
#undef A_
}

// ---------------------------------------------------------------------------
// Kernel 0 (32 blocks): block 0 computes deg vectors + zeroes hist; each
// block solves its pattern's lap_true and writes the evT/qT tables.
// misc layout (floats): [0..4] degP, [5..9] degT,
//                       [10..329] evT[32][5][2], [330..649] qT[32][5][2]
// ---------------------------------------------------------------------------
__global__ __launch_bounds__(64) void eig_init(const float* __restrict__ yt,
                                               const float* __restrict__ yp,
                                               float* __restrict__ misc,
                                               unsigned int* __restrict__ hist)
{
#pragma clang fp contract(off)
  __shared__ float sm[25];
  const int t = threadIdx.x;
  const int pat = blockIdx.x;
  if (pat == 0){
    if (t < 32) hist[t] = 0;
    if (t < 5){
      float xp[5], xt[5];
      for (int j = 0; j < 5; ++j){ xp[j] = yp[t*5+j]; xt[j] = yt[t*5+j]; }
      float cs = 0.f;
      for (int i = 0; i < 5; ++i){
        bool ci = (xp[i] != 0.f);
        float base = ci ? xp[t] : (1.f - xp[t]);
        float m2 = 2.f*base - 1.f;
        cs += (i == t) ? 0.f : m2;
      }
      misc[t] = cs - 1.f;                 // degP[t]
      float cs2 = 0.f;
      for (int i = 0; i < 5; ++i){
        bool ci = (xt[i] != 0.f);
        float base = ci ? xt[t] : (1.f - xt[t]);
        float m2 = 2.f*base - 1.f;
        cs2 += (i == t) ? 0.f : m2;
      }
      misc[5 + t] = cs2 - 1.f;            // degT[t]
    }
  }
  if (t == 0){
    // recompute degT locally (no cross-block dependency)
    float degT[5];
    #pragma unroll
    for (int r = 0; r < 5; ++r){
      float xr[5];
      #pragma unroll
      for (int j = 0; j < 5; ++j) xr[j] = yt[r*5+j];
      float cs2 = 0.f;
      #pragma unroll
      for (int i = 0; i < 5; ++i){
        bool ci = (xr[i] != 0.f);
        float base = ci ? xr[r] : (1.f - xr[r]);
        float m2 = 2.f*base - 1.f;
        cs2 += (i == r) ? 0.f : m2;
      }
      degT[r] = cs2 - 1.f;
    }
    float xv[5];
    #pragma unroll
    for (int j = 0; j < 5; ++j) xv[j] = ((pat >> j) & 1) ? 1.f : 0.f;
    #pragma unroll
    for (int i = 0; i < 5; ++i){
      bool ci = (xv[i] != 0.f);
      #pragma unroll
      for (int j = 0; j < 5; ++j){
        float base = ci ? xv[j] : (1.f - xv[j]);
        float m2 = 2.f*base - 1.f;
        float adj = (i == j) ? 0.f : m2;
        sm[j*5 + i] = degT[j] - adj;      // lap_true (column-major)
      }
    }
    sgeev5<1>(sm);
    float er[5], ei[5];
    #pragma unroll
    for (int kx = 0; kx < 5; ++kx){ er[kx] = sm[kx]; ei[kx] = sm[5+kx]; }
    float tr = 0.f, ti = 0.f;
    #pragma unroll
    for (int kx = 0; kx < 5; ++kx){ tr += er[kx]; ti += ei[kx]; }
    float den = tr*tr + ti*ti;
    float cr = 0.f, cii = 0.f;
    #pragma unroll
    for (int kx = 0; kx < 5; ++kx){
      misc[10 + pat*10 + 2*kx]     = er[kx];
      misc[10 + pat*10 + 2*kx + 1] = ei[kx];
      cr += er[kx]; cii += ei[kx];
      misc[330 + pat*10 + 2*kx]     = (cr*tr + cii*ti)/den;
      misc[330 + pat*10 + 2*kx + 1] = (cii*tr - cr*ti)/den;
    }
  }
}

// ---------------------------------------------------------------------------
// Kernel 1: per-batch pred eigensolve + accumulate per-block partials.
// LDS: H transposed [25][256] -> bank = tid%32 always (zero conflicts).
// partials[block][0..9]  = sum of cums_pred[k]/total_pred (re,im interleaved)
// partials[block][10..14]= sum of |ev_pred[k]-ev_true[k]|^2
// ---------------------------------------------------------------------------
__global__ __launch_bounds__(256, 6) void eig_main(const float* __restrict__ yt,
                                                   const float* __restrict__ yp,
                                                   double* __restrict__ partials,
                                                   unsigned int* __restrict__ hist,
                                                   const float* __restrict__ misc,
                                                   int nb)
{
#pragma clang fp contract(off)
  __shared__ float sm[25*256];
  __shared__ double red[4][16];
  __shared__ unsigned int hloc[32];
  const int tid = threadIdx.x;
  const int b = blockIdx.x*256 + tid;
  if (tid < 32) hloc[tid] = 0;
  __syncthreads();

  double vals[15];
  #pragma unroll
  for (int q = 0; q < 15; ++q) vals[q] = 0.0;

  if (b < nb){
    float* h = &sm[tid];                 // element idx at h[idx*256]
    float x[5];
    #pragma unroll
    for (int j = 0; j < 5; ++j) x[j] = yp[b*5 + j];
    float degp[5];
    #pragma unroll
    for (int j = 0; j < 5; ++j) degp[j] = misc[j];
    #pragma unroll
    for (int i = 0; i < 5; ++i){
      const bool ci = (x[i] != 0.f);
      #pragma unroll
      for (int j = 0; j < 5; ++j){
        float base = ci ? x[j] : (1.f - x[j]);
        float m2 = 2.f*base - 1.f;
        float adj = (i == j) ? 0.f : m2;
        h[(j*5 + i)*256] = degp[j] - adj; // lap_pred (column-major)
      }
    }
    sgeev5<256>(h);
    float er[5], ei[5];
    #pragma unroll
    for (int kx = 0; kx < 5; ++kx){ er[kx] = h[kx*256]; ei[kx] = h[(5+kx)*256]; }
    float tr = 0.f, ti = 0.f;
    #pragma unroll
    for (int kx = 0; kx < 5; ++kx){ tr += er[kx]; ti += ei[kx]; }
    float den = tr*tr + ti*ti;
    float cr = 0.f, cii = 0.f;
    #pragma unroll
    for (int kx = 0; kx < 5; ++kx){
      cr += er[kx]; cii += ei[kx];
      float qr = (cr*tr + cii*ti)/den;
      float qi = (cii*tr - cr*ti)/den;
      vals[2*kx]   = (double)qr;
      vals[2*kx+1] = (double)qi;
    }
    int p = 0;
    #pragma unroll
    for (int j = 0; j < 5; ++j){ if (yt[b*5 + j] != 0.f) p |= (1 << j); }
    #pragma unroll
    for (int kx = 0; kx < 5; ++kx){
      float dr = er[kx] - misc[10 + p*10 + 2*kx];
      float di = ei[kx] - misc[10 + p*10 + 2*kx + 1];
      vals[10 + kx] = (double)dr*(double)dr + (double)di*(double)di;
    }
    atomicAdd(&hloc[p], 1u);
  }

  const int lane = tid & 63, wid = tid >> 6;
  #pragma unroll
  for (int q = 0; q < 15; ++q){
    double v = vals[q];
    #pragma unroll
    for (int off = 32; off >= 1; off >>= 1) v += __shfl_down(v, off, 64);
    if (lane == 0) red[wid][q] = v;
  }
  __syncthreads();
  if (tid == 0){
    #pragma unroll
    for (int q = 0; q < 15; ++q)
      partials[(size_t)blockIdx.x*15 + q] = red[0][q] + red[1][q] + red[2][q] + red[3][q];
  }
  if (tid < 32){
    unsigned int cv = hloc[tid];
    if (cv) atomicAdd(&hist[tid], cv);
  }
}

// ---------------------------------------------------------------------------
// Kernel 2: reduce partials, energies -> k_pred/k_true -> min_k -> distance.
// ---------------------------------------------------------------------------
__global__ __launch_bounds__(256) void eig_final(const double* __restrict__ partials,
                                                 const unsigned int* __restrict__ hist,
                                                 const float* __restrict__ misc,
                                                 float* __restrict__ out,
                                                 int nb, int nblk)
{
#pragma clang fp contract(off)
  __shared__ double r2[4][16];
  const int tid = threadIdx.x;
  double acc[15];
  #pragma unroll
  for (int q = 0; q < 15; ++q) acc[q] = 0.0;
  for (int ib = tid; ib < nblk; ib += 256){
    #pragma unroll
    for (int q = 0; q < 15; ++q) acc[q] += partials[(size_t)ib*15 + q];
  }
  const int lane = tid & 63, wid = tid >> 6;
  #pragma unroll
  for (int q = 0; q < 15; ++q){
    double v = acc[q];
    #pragma unroll
    for (int off = 32; off >= 1; off >>= 1) v += __shfl_down(v, off, 64);
    if (lane == 0) r2[wid][q] = v;
  }
  __syncthreads();
  if (tid == 0){
    double tot[15];
    for (int q = 0; q < 15; ++q) tot[q] = r2[0][q] + r2[1][q] + r2[2][q] + r2[3][q];
    const double Bd = (double)nb;
    int kp = 5;
    for (int kx = 0; kx < 5; ++kx){
      double re = tot[2*kx]/Bd, im = tot[2*kx+1]/Bd;
      double e = sqrt(re*re + im*im);
      if (e > 0.85){ kp = kx + 1; break; }
    }
    int kt = 5;
    for (int kx = 0; kx < 5; ++kx){
      double re = 0.0, im = 0.0;
      for (int p = 0; p < 32; ++p){
        double cnt = (double)hist[p];
        re += cnt * (double)misc[330 + p*10 + 2*kx];
        im += cnt * (double)misc[330 + p*10 + 2*kx + 1];
      }
      re /= Bd; im /= Bd;
      double e = sqrt(re*re + im*im);
      if (e > 0.85){ kt = kx + 1; break; }
    }
    int mink = (kp < kt) ? kp : kt;
    double d2 = 0.0;
    for (int j = 0; j < mink; ++j) d2 += tot[10 + j];
    out[0] = (float)sqrt(d2);
  }
}

extern "C" void kernel_launch(void* const* d_in, const int* in_sizes, int n_in,
                              void* d_out, int out_size, void* d_ws, size_t ws_size,
                              hipStream_t stream)
{
  const float* yt = (const float*)d_in[0];   // y_true (0/1 floats)
  const float* yp = (const float*)d_in[1];   // y_pred (uniform floats)
  float* out = (float*)d_out;
  const int nb = in_sizes[0] / 5;
  const int nblk = (nb + 255) / 256;

  char* ws = (char*)d_ws;
  double* partials = (double*)ws;                       // nblk*15 doubles
  size_t off = (size_t)nblk * 15 * sizeof(double);
  off = (off + 255) & ~(size_t)255;
  unsigned int* hist = (unsigned int*)(ws + off);       // 32 u32
  float* misc = (float*)(ws + off + 256);               // 650 floats

  eig_init<<<32, 64, 0, stream>>>(yt, yp, misc, hist);
  eig_main<<<nblk, 256, 0, stream>>>(yt, yp, partials, hist, misc, nb);
  eig_final<<<1, 256, 0, stream>>>(partials, hist, misc, out, nb, nblk);
}